// Round 1
// baseline (31640.375 us; speedup 1.0000x reference)
//
#include <hip/hip_runtime.h>
#include <hip/hip_bf16.h>
#include <math.h>

#define SEQ 4096
#define HDIM 1024
#define G3 3072
#define NB 128        // scan blocks
#define JB 8          // h indices per block
#define NROWS 24      // 3*JB rows of W_hh per block

// ws layout (in floats):
// [0, SEQ*G3)              gi_all  (50.33 MB)
// [GI, GI+2*HDIM)          hbuf double buffer
// [GI+2*HDIM, +NB)         flags (as uint)
#define GI_ELEMS (SEQ * G3)
#define HBUF_OFF GI_ELEMS
#define FLAGS_OFF (HBUF_OFF + 2 * HDIM)
#define WS_NEEDED_BYTES ((size_t)(FLAGS_OFF + NB) * 4)

__global__ void k_init(float* ws) {
    int tid = blockIdx.x * 256 + threadIdx.x;
    if (tid < 2 * HDIM) ws[HBUF_OFF + tid] = 0.0f;
    if (tid < NB) ((unsigned*)(ws + FLAGS_OFF))[tid] = 0u;
}

__global__ void k_ws_too_small(float* out) {
    if (threadIdx.x < 2) out[threadIdx.x] = -12345.0f;  // sentinel
}

// ---------------- K1: gi_all = emb[X] @ W_ih^T + b_ih ----------------
// fp32 tiled GEMM, 64(t) x 64(m) tile, BK=16, 256 threads, 4x4 microtile.
__global__ __launch_bounds__(256)
void k_gi(const int* __restrict__ X, const float* __restrict__ emb,
          const float* __restrict__ W_ih, const float* __restrict__ b_ih,
          float* __restrict__ gi) {
    __shared__ float As[16][64];
    __shared__ float Bs[16][64];
    __shared__ int Xl[64];

    const int t0 = blockIdx.x * 64;
    const int m0 = blockIdx.y * 64;
    const int tid = threadIdx.x;

    if (tid < 64) Xl[tid] = X[t0 + tid];
    __syncthreads();

    const int lrow = tid & 63;   // row within tile for staging loads
    const int kq = tid >> 6;     // 0..3 -> covers k = kq*4 .. +4
    const int tx = tid & 15, ty = tid >> 4;

    const float* embr = emb + (size_t)Xl[lrow] * HDIM;
    const float* wrow = W_ih + (size_t)(m0 + lrow) * HDIM;

    float acc[4][4] = {};

    for (int k0 = 0; k0 < HDIM; k0 += 16) {
        float4 a = *(const float4*)(embr + k0 + kq * 4);
        float4 bv = *(const float4*)(wrow + k0 + kq * 4);
        __syncthreads();  // previous iter's LDS reads done
        As[kq * 4 + 0][lrow] = a.x;  As[kq * 4 + 1][lrow] = a.y;
        As[kq * 4 + 2][lrow] = a.z;  As[kq * 4 + 3][lrow] = a.w;
        Bs[kq * 4 + 0][lrow] = bv.x; Bs[kq * 4 + 1][lrow] = bv.y;
        Bs[kq * 4 + 2][lrow] = bv.z; Bs[kq * 4 + 3][lrow] = bv.w;
        __syncthreads();
        #pragma unroll
        for (int k = 0; k < 16; ++k) {
            float4 av = *(const float4*)&As[k][ty * 4];
            float4 bw = *(const float4*)&Bs[k][tx * 4];
            float a_[4] = {av.x, av.y, av.z, av.w};
            float b_[4] = {bw.x, bw.y, bw.z, bw.w};
            #pragma unroll
            for (int i = 0; i < 4; ++i)
                #pragma unroll
                for (int j = 0; j < 4; ++j)
                    acc[i][j] += a_[i] * b_[j];
        }
    }

    float4 bj = *(const float4*)&b_ih[m0 + tx * 4];
    #pragma unroll
    for (int i = 0; i < 4; ++i) {
        float4 o;
        o.x = acc[i][0] + bj.x; o.y = acc[i][1] + bj.y;
        o.z = acc[i][2] + bj.z; o.w = acc[i][3] + bj.w;
        *(float4*)&gi[(size_t)(t0 + ty * 4 + i) * G3 + m0 + tx * 4] = o;
    }
}

// ---------------- K2: persistent GRU scan ----------------
// 128 blocks x 256 threads (4 waves). Block b owns h[8b..8b+8).
// LDS-resident 24 rows of W_hh (r/z/n for its 8 indices). Flag-synced steps.
__global__ __launch_bounds__(256)
void k_scan(const float* __restrict__ W_hh, const float* __restrict__ b_hh,
            float* ws) {
    __shared__ float Wl[NROWS][HDIM];   // 96 KB
    __shared__ float hl[HDIM];          // 4 KB
    __shared__ float ghl[NROWS];
    __shared__ float bl[NROWS];

    const int b = blockIdx.x;
    const int tid = threadIdx.x;
    const int wv = tid >> 6, ln = tid & 63;
    const int j0 = b * JB;

    const float* gi = ws;
    float* hbuf = ws + HBUF_OFF;
    unsigned* flags = (unsigned*)(ws + FLAGS_OFF);

    // Preload the 24 W_hh rows this block needs (gates r,z,n for j0..j0+7)
    for (int q = 0; q < NROWS; ++q) {
        const int g = q >> 3, i = q & 7;
        const float* src = W_hh + (size_t)(g * HDIM + j0 + i) * HDIM;
        *(float4*)&Wl[q][tid * 4] = *(const float4*)(src + tid * 4);
    }
    if (tid < NROWS) {
        const int g = tid >> 3, i = tid & 7;
        bl[tid] = b_hh[g * HDIM + j0 + i];
    }
    __syncthreads();

    for (int t = 0; t < SEQ; ++t) {
        // Prefetch input-side gate values early (independent of h)
        float gi_r = 0.f, gi_z = 0.f, gi_n = 0.f;
        if (wv == 0 && ln < JB) {
            const float* gp = gi + (size_t)t * G3 + j0 + ln;
            gi_r = gp[0];
            gi_z = gp[HDIM];
            gi_n = gp[2 * HDIM];
        }

        if (wv == 0) {
            if (t > 0) {
                const unsigned tt = (unsigned)t;
                while (true) {
                    unsigned f1 = __hip_atomic_load(&flags[ln], __ATOMIC_RELAXED,
                                                    __HIP_MEMORY_SCOPE_AGENT);
                    unsigned f2 = __hip_atomic_load(&flags[ln + 64], __ATOMIC_RELAXED,
                                                    __HIP_MEMORY_SCOPE_AGENT);
                    if (__all(f1 >= tt && f2 >= tt)) break;
                    __builtin_amdgcn_s_sleep(1);
                }
                __threadfence();  // acquire: invalidate stale cache lines
            }
            // stage h (output of step t-1; zeros buffer for t=0) into LDS
            const float* hsrc = hbuf + (size_t)((t + 1) & 1) * HDIM;
            #pragma unroll
            for (int c = 0; c < 4; ++c)
                *(float4*)&hl[c * 256 + ln * 4] = *(const float4*)(hsrc + c * 256 + ln * 4);
        }
        __syncthreads();

        // Each wave: 6 rows; lane l covers columns {l*4 + 256c}
        float4 hr[4];
        #pragma unroll
        for (int c = 0; c < 4; ++c) hr[c] = *(float4*)&hl[c * 256 + ln * 4];

        #pragma unroll
        for (int r6 = 0; r6 < 6; ++r6) {
            const int r = wv * 6 + r6;
            float s = 0.0f;
            #pragma unroll
            for (int c = 0; c < 4; ++c) {
                float4 w = *(float4*)&Wl[r][c * 256 + ln * 4];
                s += w.x * hr[c].x + w.y * hr[c].y + w.z * hr[c].z + w.w * hr[c].w;
            }
            #pragma unroll
            for (int off = 32; off; off >>= 1) s += __shfl_xor(s, off);
            if (ln == 0) ghl[r] = s;
        }
        __syncthreads();

        // Combine gates and publish (wave 0 only; waves 1-3 wait at the
        // next iteration's barrier, so ghl/hl cannot be overwritten early).
        if (wv == 0) {
            if (ln < JB) {
                const float gr = ghl[ln]       + bl[ln];
                const float gz = ghl[8 + ln]   + bl[8 + ln];
                const float gn = ghl[16 + ln]  + bl[16 + ln];
                const float r = 1.0f / (1.0f + __expf(-(gi_r + gr)));
                const float z = 1.0f / (1.0f + __expf(-(gi_z + gz)));
                const float n = tanhf(gi_n + r * gn);
                const float hnew = (1.0f - z) * n + z * hl[j0 + ln];
                hbuf[(size_t)(t & 1) * HDIM + j0 + ln] = hnew;
            }
            __threadfence();  // release: drain h stores to coherence point
            if (ln == 0)
                __hip_atomic_store(&flags[b], (unsigned)(t + 1), __ATOMIC_RELAXED,
                                   __HIP_MEMORY_SCOPE_AGENT);
        }
    }
}

// ---------------- K3: head ----------------
__global__ void k_head(const float* __restrict__ W1, const float* __restrict__ b1,
                       const float* __restrict__ W2, const float* __restrict__ b2,
                       const float* __restrict__ ws, float* __restrict__ out) {
    const float* h = ws + HBUF_OFF + (size_t)((SEQ - 1) & 1) * HDIM;
    const int ln = threadIdx.x;
    __shared__ float zsh[8];
    for (int m = 0; m < 8; ++m) {
        float s = 0.0f;
        #pragma unroll
        for (int c = 0; c < 16; ++c) s += h[c * 64 + ln] * W1[m * HDIM + c * 64 + ln];
        #pragma unroll
        for (int off = 32; off; off >>= 1) s += __shfl_xor(s, off);
        if (ln == 0) zsh[m] = fmaxf(s + b1[m], 0.0f);
    }
    __syncthreads();
    if (ln < 2) {
        float s = b2[ln];
        #pragma unroll
        for (int m = 0; m < 8; ++m) s += zsh[m] * W2[ln * 8 + m];
        out[ln] = 1.0f / (1.0f + expf(-s));
    }
}

extern "C" void kernel_launch(void* const* d_in, const int* in_sizes, int n_in,
                              void* d_out, int out_size, void* d_ws, size_t ws_size,
                              hipStream_t stream) {
    const int*   X    = (const int*)d_in[0];
    const float* emb  = (const float*)d_in[1];
    const float* W_ih = (const float*)d_in[2];
    const float* W_hh = (const float*)d_in[3];
    const float* b_ih = (const float*)d_in[4];
    const float* b_hh = (const float*)d_in[5];
    const float* W1   = (const float*)d_in[6];
    const float* b1   = (const float*)d_in[7];
    const float* W2   = (const float*)d_in[8];
    const float* b2   = (const float*)d_in[9];
    float* out = (float*)d_out;
    float* ws  = (float*)d_ws;

    if (ws_size < WS_NEEDED_BYTES) {
        k_ws_too_small<<<1, 64, 0, stream>>>(out);
        return;
    }

    k_init<<<dim3(9), dim3(256), 0, stream>>>(ws);
    dim3 g1(SEQ / 64, G3 / 64);
    k_gi<<<g1, dim3(256), 0, stream>>>(X, emb, W_ih, b_ih, ws);
    k_scan<<<dim3(NB), dim3(256), 0, stream>>>(W_hh, b_hh, ws);
    k_head<<<dim3(1), dim3(64), 0, stream>>>(W1, b1, W2, b2, ws, out);
}

// Round 2
// 24521.661 us; speedup vs baseline: 1.2903x; 1.2903x over previous
//
#include <hip/hip_runtime.h>
#include <hip/hip_bf16.h>
#include <math.h>

#define SEQ 4096
#define HDIM 1024
#define G3 3072
#define NB 128        // scan blocks
#define JB 8          // h indices per block
#define NROWS 24      // 3*JB rows of W_hh per block

typedef float f32x4 __attribute__((ext_vector_type(4)));

// ws layout (in floats):
// [0, SEQ*G3)              gi_all  (50.33 MB)
// [GI, GI+2*HDIM)          hbuf double buffer
// [GI+2*HDIM, +NB)         flags (as uint)
#define GI_ELEMS (SEQ * G3)
#define HBUF_OFF GI_ELEMS
#define FLAGS_OFF (HBUF_OFF + 2 * HDIM)
#define WS_NEEDED_BYTES ((size_t)(FLAGS_OFF + NB) * 4)

__global__ void k_init(float* ws) {
    int tid = blockIdx.x * 256 + threadIdx.x;
    if (tid < 2 * HDIM) ws[HBUF_OFF + tid] = 0.0f;
    if (tid < NB) ((unsigned*)(ws + FLAGS_OFF))[tid] = 0u;
}

__global__ void k_ws_too_small(float* out) {
    if (threadIdx.x < 2) out[threadIdx.x] = -12345.0f;  // sentinel
}

// ---- uncached (MALL-coherent) access helpers: bypass L1+L2 via sc0 sc1 ----
__device__ __forceinline__ void st_cg_f(float* p, float v) {
    asm volatile("global_store_dword %0, %1, off sc0 sc1" :: "v"(p), "v"(v) : "memory");
}
__device__ __forceinline__ void st_cg_u(unsigned* p, unsigned v) {
    asm volatile("global_store_dword %0, %1, off sc0 sc1" :: "v"(p), "v"(v) : "memory");
}

// ---------------- K1: gi_all = emb[X] @ W_ih^T + b_ih ----------------
// fp32 tiled GEMM, 64(t) x 64(m) tile, BK=16, 256 threads, 4x4 microtile.
__global__ __launch_bounds__(256)
void k_gi(const int* __restrict__ X, const float* __restrict__ emb,
          const float* __restrict__ W_ih, const float* __restrict__ b_ih,
          float* __restrict__ gi) {
    __shared__ float As[16][64];
    __shared__ float Bs[16][64];
    __shared__ int Xl[64];

    const int t0 = blockIdx.x * 64;
    const int m0 = blockIdx.y * 64;
    const int tid = threadIdx.x;

    if (tid < 64) Xl[tid] = X[t0 + tid];
    __syncthreads();

    const int lrow = tid & 63;   // row within tile for staging loads
    const int kq = tid >> 6;     // 0..3 -> covers k = kq*4 .. +4
    const int tx = tid & 15, ty = tid >> 4;

    const float* embr = emb + (size_t)Xl[lrow] * HDIM;
    const float* wrow = W_ih + (size_t)(m0 + lrow) * HDIM;

    float acc[4][4] = {};

    for (int k0 = 0; k0 < HDIM; k0 += 16) {
        float4 a = *(const float4*)(embr + k0 + kq * 4);
        float4 bv = *(const float4*)(wrow + k0 + kq * 4);
        __syncthreads();  // previous iter's LDS reads done
        As[kq * 4 + 0][lrow] = a.x;  As[kq * 4 + 1][lrow] = a.y;
        As[kq * 4 + 2][lrow] = a.z;  As[kq * 4 + 3][lrow] = a.w;
        Bs[kq * 4 + 0][lrow] = bv.x; Bs[kq * 4 + 1][lrow] = bv.y;
        Bs[kq * 4 + 2][lrow] = bv.z; Bs[kq * 4 + 3][lrow] = bv.w;
        __syncthreads();
        #pragma unroll
        for (int k = 0; k < 16; ++k) {
            float4 av = *(const float4*)&As[k][ty * 4];
            float4 bw = *(const float4*)&Bs[k][tx * 4];
            float a_[4] = {av.x, av.y, av.z, av.w};
            float b_[4] = {bw.x, bw.y, bw.z, bw.w};
            #pragma unroll
            for (int i = 0; i < 4; ++i)
                #pragma unroll
                for (int j = 0; j < 4; ++j)
                    acc[i][j] += a_[i] * b_[j];
        }
    }

    float4 bj = *(const float4*)&b_ih[m0 + tx * 4];
    #pragma unroll
    for (int i = 0; i < 4; ++i) {
        float4 o;
        o.x = acc[i][0] + bj.x; o.y = acc[i][1] + bj.y;
        o.z = acc[i][2] + bj.z; o.w = acc[i][3] + bj.w;
        *(float4*)&gi[(size_t)(t0 + ty * 4 + i) * G3 + m0 + tx * 4] = o;
    }
}

// ---------------- K2: persistent GRU scan ----------------
// 128 blocks x 256 threads (4 waves). Block b owns h[8b..8b+8).
// W_hh rows live in per-thread REGISTERS (6 rows/wave, 16 cols/lane).
// Cross-block h/flag exchange entirely via uncached sc0sc1 -> no fences.
__global__ __launch_bounds__(256)
void k_scan(const float* __restrict__ W_hh, const float* __restrict__ b_hh,
            float* ws) {
    __shared__ float ghl[NROWS];

    const int b = blockIdx.x;
    const int tid = threadIdx.x;
    const int wv = tid >> 6, ln = tid & 63;
    const int j0 = b * JB;

    const float* gi = ws;
    float* hbuf = ws + HBUF_OFF;
    unsigned* flags = (unsigned*)(ws + FLAGS_OFF);

    // ---- preload this thread's W_hh fragment into registers ----
    // wave wv handles rows q = wv*6 .. wv*6+5 (q: gate g=q>>3, idx i=q&7)
    // lane ln covers columns {ln*4 + 256c + e}, c=0..3, e=0..3
    f32x4 w[6][4];
    #pragma unroll
    for (int r6 = 0; r6 < 6; ++r6) {
        const int q = wv * 6 + r6;
        const int g = q >> 3, i = q & 7;
        const float* src = W_hh + ((size_t)(g * HDIM + j0 + i)) * HDIM + ln * 4;
        #pragma unroll
        for (int c = 0; c < 4; ++c) w[r6][c] = *(const f32x4*)(src + c * 256);
    }

    // wave0: per-lane biases for the gate combine (lanes 0..7 meaningful)
    float blr = 0.f, blz = 0.f, bln_ = 0.f;
    if (wv == 0) {
        const int i = ln & 7;
        blr  = b_hh[j0 + i];
        blz  = b_hh[HDIM + j0 + i];
        bln_ = b_hh[2 * HDIM + j0 + i];
    }

    const unsigned* fp0 = flags + ln;          // covers blocks 0..63
    // flags+ln+64 addressed via offset:256 in the poll asm

    for (int t = 0; t < SEQ; ++t) {
        // gi prefetch (cached, read-only): overlaps the poll wait
        float gi_r = 0.f, gi_z = 0.f, gi_n = 0.f;
        if (wv == 0) {
            const float* gp = gi + (size_t)t * G3 + j0 + (ln & 7);
            gi_r = gp[0];
            gi_z = gp[HDIM];
            gi_n = gp[2 * HDIM];
        }

        // ---- poll: all waves wait until every block published step t ----
        if (t > 0) {
            const unsigned tt = (unsigned)t;
            for (;;) {
                unsigned fa, fb;
                asm volatile(
                    "global_load_dword %0, %2, off sc0 sc1\n\t"
                    "global_load_dword %1, %2, off offset:256 sc0 sc1\n\t"
                    "s_waitcnt vmcnt(0)"
                    : "=&v"(fa), "=&v"(fb) : "v"(fp0) : "memory");
                if (__all(fa >= tt && fb >= tt)) break;
            }
        }

        // ---- load the h slices this lane needs (uncached, one wait) ----
        const float* hsrc = hbuf + (size_t)((t + 1) & 1) * HDIM;
        const float* hb = hsrc + ln * 4;
        const float* pp = hsrc + j0 + (ln & 7);   // own h (for gate combine)
        f32x4 h0, h1, h2, h3; float hp;
        asm volatile(
            "global_load_dwordx4 %0, %5, off sc0 sc1\n\t"
            "global_load_dwordx4 %1, %5, off offset:1024 sc0 sc1\n\t"
            "global_load_dwordx4 %2, %5, off offset:2048 sc0 sc1\n\t"
            "global_load_dwordx4 %3, %5, off offset:3072 sc0 sc1\n\t"
            "global_load_dword   %4, %6, off sc0 sc1\n\t"
            "s_waitcnt vmcnt(0)"
            : "=&v"(h0), "=&v"(h1), "=&v"(h2), "=&v"(h3), "=&v"(hp)
            : "v"(hb), "v"(pp)
            : "memory");

        // ---- 6 dot products per wave, register weights ----
        #pragma unroll
        for (int r6 = 0; r6 < 6; ++r6) {
            float s = w[r6][0].x * h0.x + w[r6][0].y * h0.y + w[r6][0].z * h0.z + w[r6][0].w * h0.w
                    + w[r6][1].x * h1.x + w[r6][1].y * h1.y + w[r6][1].z * h1.z + w[r6][1].w * h1.w
                    + w[r6][2].x * h2.x + w[r6][2].y * h2.y + w[r6][2].z * h2.z + w[r6][2].w * h2.w
                    + w[r6][3].x * h3.x + w[r6][3].y * h3.y + w[r6][3].z * h3.z + w[r6][3].w * h3.w;
            #pragma unroll
            for (int off = 32; off; off >>= 1) s += __shfl_xor(s, off);
            if (ln == 0) ghl[wv * 6 + r6] = s;
        }
        __syncthreads();

        // ---- gate combine + publish (wave 0) ----
        if (wv == 0) {
            if (ln < JB) {
                const float gr = ghl[ln]      + blr;
                const float gz = ghl[8 + ln]  + blz;
                const float gn = ghl[16 + ln] + bln_;
                const float r = 1.0f / (1.0f + __expf(-(gi_r + gr)));
                const float z = 1.0f / (1.0f + __expf(-(gi_z + gz)));
                const float n = tanhf(gi_n + r * gn);
                const float hnew = (1.0f - z) * n + z * hp;
                st_cg_f(hbuf + (size_t)(t & 1) * HDIM + j0 + ln, hnew);
            }
            // release: uncached h stores reach MALL before flag flips
            asm volatile("s_waitcnt vmcnt(0)" ::: "memory");
            if (ln == 0) st_cg_u(&flags[b], (unsigned)(t + 1));
        }
        // waves 1-3 run ahead into step t+1; their next ghl write is gated
        // by the poll (needs flags[b] >= t+1, set only after wave0 read ghl)
    }
}

// ---------------- K3: head ----------------
__global__ void k_head(const float* __restrict__ W1, const float* __restrict__ b1,
                       const float* __restrict__ W2, const float* __restrict__ b2,
                       const float* __restrict__ ws, float* __restrict__ out) {
    const float* h = ws + HBUF_OFF + (size_t)((SEQ - 1) & 1) * HDIM;
    const int ln = threadIdx.x;
    __shared__ float zsh[8];
    for (int m = 0; m < 8; ++m) {
        float s = 0.0f;
        #pragma unroll
        for (int c = 0; c < 16; ++c) s += h[c * 64 + ln] * W1[m * HDIM + c * 64 + ln];
        #pragma unroll
        for (int off = 32; off; off >>= 1) s += __shfl_xor(s, off);
        if (ln == 0) zsh[m] = fmaxf(s + b1[m], 0.0f);
    }
    __syncthreads();
    if (ln < 2) {
        float s = b2[ln];
        #pragma unroll
        for (int m = 0; m < 8; ++m) s += zsh[m] * W2[ln * 8 + m];
        out[ln] = 1.0f / (1.0f + expf(-s));
    }
}

extern "C" void kernel_launch(void* const* d_in, const int* in_sizes, int n_in,
                              void* d_out, int out_size, void* d_ws, size_t ws_size,
                              hipStream_t stream) {
    const int*   X    = (const int*)d_in[0];
    const float* emb  = (const float*)d_in[1];
    const float* W_ih = (const float*)d_in[2];
    const float* W_hh = (const float*)d_in[3];
    const float* b_ih = (const float*)d_in[4];
    const float* b_hh = (const float*)d_in[5];
    const float* W1   = (const float*)d_in[6];
    const float* b1   = (const float*)d_in[7];
    const float* W2   = (const float*)d_in[8];
    const float* b2   = (const float*)d_in[9];
    float* out = (float*)d_out;
    float* ws  = (float*)d_ws;

    if (ws_size < WS_NEEDED_BYTES) {
        k_ws_too_small<<<1, 64, 0, stream>>>(out);
        return;
    }

    k_init<<<dim3(9), dim3(256), 0, stream>>>(ws);
    dim3 g1(SEQ / 64, G3 / 64);
    k_gi<<<g1, dim3(256), 0, stream>>>(X, emb, W_ih, b_ih, ws);
    k_scan<<<dim3(NB), dim3(256), 0, stream>>>(W_hh, b_hh, ws);
    k_head<<<dim3(1), dim3(64), 0, stream>>>(W1, b1, W2, b2, ws, out);
}

// Round 3
// 12356.216 us; speedup vs baseline: 2.5607x; 1.9846x over previous
//
#include <hip/hip_runtime.h>
#include <hip/hip_bf16.h>
#include <math.h>

#define SEQ 4096
#define HDIM 1024
#define G3 3072
#define NB 128        // scan blocks
#define JB 8          // h indices per block
#define NROWS 24      // 3*JB rows of W_hh per block

typedef float    f32x4 __attribute__((ext_vector_type(4)));
typedef unsigned u32x4 __attribute__((ext_vector_type(4)));
typedef unsigned u32x2 __attribute__((ext_vector_type(2)));

// ws layout (dwords):
// [0, SEQ*G3)                    gi_all (50.33 MB)
// [PAIRS_OFF, +4096)             h pair region: 2 buffers x 1024 pairs x (val,tag)
#define GI_ELEMS  (SEQ * G3)
#define PAIRS_OFF GI_ELEMS
#define PAIR_DWORDS (2 * HDIM * 2)
#define WS_NEEDED_BYTES ((size_t)(GI_ELEMS + PAIR_DWORDS) * 4)

// zero both pair buffers (val=0, tag=0) with uncached stores
__global__ void k_init(float* ws) {
    unsigned* pairs = (unsigned*)(ws + PAIRS_OFF);
    int tid = blockIdx.x * 256 + threadIdx.x;   // 0..2047 (one pair each)
    u32x2 z; z.x = 0u; z.y = 0u;
    unsigned* p = pairs + (size_t)tid * 2;
    asm volatile("global_store_dwordx2 %0, %1, off sc0 sc1" :: "v"(p), "v"(z) : "memory");
}

__global__ void k_ws_too_small(float* out) {
    if (threadIdx.x < 2) out[threadIdx.x] = -12345.0f;  // sentinel
}

// ---------------- K1: gi_all = emb[X] @ W_ih^T + b_ih ----------------
__global__ __launch_bounds__(256)
void k_gi(const int* __restrict__ X, const float* __restrict__ emb,
          const float* __restrict__ W_ih, const float* __restrict__ b_ih,
          float* __restrict__ gi) {
    __shared__ float As[16][64];
    __shared__ float Bs[16][64];
    __shared__ int Xl[64];

    const int t0 = blockIdx.x * 64;
    const int m0 = blockIdx.y * 64;
    const int tid = threadIdx.x;

    if (tid < 64) Xl[tid] = X[t0 + tid];
    __syncthreads();

    const int lrow = tid & 63;
    const int kq = tid >> 6;
    const int tx = tid & 15, ty = tid >> 4;

    const float* embr = emb + (size_t)Xl[lrow] * HDIM;
    const float* wrow = W_ih + (size_t)(m0 + lrow) * HDIM;

    float acc[4][4] = {};

    for (int k0 = 0; k0 < HDIM; k0 += 16) {
        float4 a = *(const float4*)(embr + k0 + kq * 4);
        float4 bv = *(const float4*)(wrow + k0 + kq * 4);
        __syncthreads();
        As[kq * 4 + 0][lrow] = a.x;  As[kq * 4 + 1][lrow] = a.y;
        As[kq * 4 + 2][lrow] = a.z;  As[kq * 4 + 3][lrow] = a.w;
        Bs[kq * 4 + 0][lrow] = bv.x; Bs[kq * 4 + 1][lrow] = bv.y;
        Bs[kq * 4 + 2][lrow] = bv.z; Bs[kq * 4 + 3][lrow] = bv.w;
        __syncthreads();
        #pragma unroll
        for (int k = 0; k < 16; ++k) {
            float4 av = *(const float4*)&As[k][ty * 4];
            float4 bw = *(const float4*)&Bs[k][tx * 4];
            float a_[4] = {av.x, av.y, av.z, av.w};
            float b_[4] = {bw.x, bw.y, bw.z, bw.w};
            #pragma unroll
            for (int i = 0; i < 4; ++i)
                #pragma unroll
                for (int j = 0; j < 4; ++j)
                    acc[i][j] += a_[i] * b_[j];
        }
    }

    float4 bj = *(const float4*)&b_ih[m0 + tx * 4];
    #pragma unroll
    for (int i = 0; i < 4; ++i) {
        float4 o;
        o.x = acc[i][0] + bj.x; o.y = acc[i][1] + bj.y;
        o.z = acc[i][2] + bj.z; o.w = acc[i][3] + bj.w;
        *(float4*)&gi[(size_t)(t0 + ty * 4 + i) * G3 + m0 + tx * 4] = o;
    }
}

// ---------------- K2: persistent GRU scan ----------------
// 128 blocks x 256 threads. Block b owns h[8b..8b+8). Weights in VGPRs.
// h exchanged as (value, tag) 8B pairs, tag = step+1 -> poll IS the data
// load; one MALL round trip per step, no flags, no fences.
__global__ __launch_bounds__(256, 1)
void k_scan(const float* __restrict__ W_hh, const float* __restrict__ b_hh,
            float* ws) {
    __shared__ float hl[HDIM];
    __shared__ float ghl[NROWS];

    const int b = blockIdx.x;
    const int tid = threadIdx.x;
    const int wv = tid >> 6, ln = tid & 63;
    const int j0 = b * JB;

    const float* gi = ws;
    unsigned* pairs = (unsigned*)(ws + PAIRS_OFF);

    // ---- preload W_hh fragment into registers and pin it there ----
    // wave wv: rows q = wv*6 .. +5 (gate g=q>>3, idx i=q&7); lane ln:
    // columns {ln*4 + 256c + e}
    f32x4 w[6][4];
    #pragma unroll
    for (int r6 = 0; r6 < 6; ++r6) {
        const int q = wv * 6 + r6;
        const int g = q >> 3, i = q & 7;
        const float* src = W_hh + ((size_t)(g * HDIM + j0 + i)) * HDIM + ln * 4;
        #pragma unroll
        for (int c = 0; c < 4; ++c) w[r6][c] = *(const f32x4*)(src + c * 256);
    }
    #pragma unroll
    for (int r6 = 0; r6 < 6; ++r6)
        #pragma unroll
        for (int c = 0; c < 4; ++c)
            asm volatile("" : "+v"(w[r6][c]));   // keep resident in VGPRs

    float blr = 0.f, blz = 0.f, bln_ = 0.f;
    if (wv == 0) {
        const int i = ln & 7;
        blr  = b_hh[j0 + i];
        blz  = b_hh[HDIM + j0 + i];
        bln_ = b_hh[2 * HDIM + j0 + i];
    }

    for (int t = 0; t < SEQ; ++t) {
        const unsigned tt = (unsigned)t;

        // gi prefetch (cached): issues before the poll, completes under it
        float gi_r = 0.f, gi_z = 0.f, gi_n = 0.f;
        if (wv == 0) {
            const float* gp = gi + (size_t)t * G3 + j0 + (ln & 7);
            gi_r = gp[0];
            gi_z = gp[HDIM];
            gi_n = gp[2 * HDIM];
        }

        // ---- fused poll+load: wave wv owns pairs [256wv, 256wv+256),
        //      lane ln the 4 pairs at 256wv+4ln (32B) ----
        unsigned* qb = pairs + (size_t)((t + 1) & 1) * 2048
                             + (unsigned)(wv * 512 + ln * 8);
        u32x4 p0, p1;
        for (;;) {
            asm volatile(
                "global_load_dwordx4 %0, %2, off sc0 sc1\n\t"
                "global_load_dwordx4 %1, %2, off offset:16 sc0 sc1\n\t"
                "s_waitcnt vmcnt(0)"
                : "=&v"(p0), "=&v"(p1) : "v"(qb) : "memory");
            if (__all((p0.y == tt) & (p0.w == tt) & (p1.y == tt) & (p1.w == tt)))
                break;
        }
        f32x4 hv;
        hv.x = __uint_as_float(p0.x); hv.y = __uint_as_float(p0.z);
        hv.z = __uint_as_float(p1.x); hv.w = __uint_as_float(p1.z);
        *(f32x4*)&hl[wv * 256 + ln * 4] = hv;
        __syncthreads();   // A: full h staged

        f32x4 h0 = *(f32x4*)&hl[ln * 4];
        f32x4 h1 = *(f32x4*)&hl[ln * 4 + 256];
        f32x4 h2 = *(f32x4*)&hl[ln * 4 + 512];
        f32x4 h3 = *(f32x4*)&hl[ln * 4 + 768];
        const float hp = hl[j0 + (ln & 7)];   // own previous-h (wave0 uses it)

        #pragma unroll
        for (int r6 = 0; r6 < 6; ++r6) {
            float s = w[r6][0].x * h0.x + w[r6][0].y * h0.y + w[r6][0].z * h0.z + w[r6][0].w * h0.w
                    + w[r6][1].x * h1.x + w[r6][1].y * h1.y + w[r6][1].z * h1.z + w[r6][1].w * h1.w
                    + w[r6][2].x * h2.x + w[r6][2].y * h2.y + w[r6][2].z * h2.z + w[r6][2].w * h2.w
                    + w[r6][3].x * h3.x + w[r6][3].y * h3.y + w[r6][3].z * h3.z + w[r6][3].w * h3.w;
            #pragma unroll
            for (int off = 32; off; off >>= 1) s += __shfl_xor(s, off);
            if (ln == 0) ghl[wv * 6 + r6] = s;
        }
        __syncthreads();   // B: ghl complete (also fences hl for next step)

        // ---- gate combine + publish (wave0 lanes 0..7) ----
        if (wv == 0 && ln < JB) {
            const float gr = ghl[ln]      + blr;
            const float gz = ghl[8 + ln]  + blz;
            const float gn = ghl[16 + ln] + bln_;
            const float r = 1.0f / (1.0f + __expf(-(gi_r + gr)));
            const float z = 1.0f / (1.0f + __expf(-(gi_z + gz)));
            const float n = tanhf(gi_n + r * gn);
            const float hnew = (1.0f - z) * n + z * hp;
            u32x2 pv; pv.x = __float_as_uint(hnew); pv.y = tt + 1u;
            unsigned* dst = pairs + (size_t)(t & 1) * 2048
                                  + (unsigned)((j0 + ln) * 2);
            asm volatile("global_store_dwordx2 %0, %1, off sc0 sc1"
                         :: "v"(dst), "v"(pv) : "memory");
        }
        // no drain needed: tag rides in the same 8B store as the value
    }
}

// ---------------- K3: head ----------------
__global__ void k_head(const float* __restrict__ W1, const float* __restrict__ b1,
                       const float* __restrict__ W2, const float* __restrict__ b2,
                       const float* __restrict__ ws, float* __restrict__ out) {
    // final h = output of step 4095 -> pair buffer 1, value at even dwords
    const unsigned* hpair = (const unsigned*)(ws + PAIRS_OFF) + 2048;
    const int ln = threadIdx.x;
    __shared__ float zsh[8];
    for (int m = 0; m < 8; ++m) {
        float s = 0.0f;
        #pragma unroll
        for (int c = 0; c < 16; ++c) {
            const int j = c * 64 + ln;
            s += __uint_as_float(hpair[2 * j]) * W1[m * HDIM + j];
        }
        #pragma unroll
        for (int off = 32; off; off >>= 1) s += __shfl_xor(s, off);
        if (ln == 0) zsh[m] = fmaxf(s + b1[m], 0.0f);
    }
    __syncthreads();
    if (ln < 2) {
        float s = b2[ln];
        #pragma unroll
        for (int m = 0; m < 8; ++m) s += zsh[m] * W2[ln * 8 + m];
        out[ln] = 1.0f / (1.0f + expf(-s));
    }
}

extern "C" void kernel_launch(void* const* d_in, const int* in_sizes, int n_in,
                              void* d_out, int out_size, void* d_ws, size_t ws_size,
                              hipStream_t stream) {
    const int*   X    = (const int*)d_in[0];
    const float* emb  = (const float*)d_in[1];
    const float* W_ih = (const float*)d_in[2];
    const float* W_hh = (const float*)d_in[3];
    const float* b_ih = (const float*)d_in[4];
    const float* b_hh = (const float*)d_in[5];
    const float* W1   = (const float*)d_in[6];
    const float* b1   = (const float*)d_in[7];
    const float* W2   = (const float*)d_in[8];
    const float* b2   = (const float*)d_in[9];
    float* out = (float*)d_out;
    float* ws  = (float*)d_ws;

    if (ws_size < WS_NEEDED_BYTES) {
        k_ws_too_small<<<1, 64, 0, stream>>>(out);
        return;
    }

    k_init<<<dim3(8), dim3(256), 0, stream>>>(ws);
    dim3 g1(SEQ / 64, G3 / 64);
    k_gi<<<g1, dim3(256), 0, stream>>>(X, emb, W_ih, b_ih, ws);
    k_scan<<<dim3(NB), dim3(256), 0, stream>>>(W_hh, b_hh, ws);
    k_head<<<dim3(1), dim3(64), 0, stream>>>(W1, b1, W2, b2, ws, out);
}